// Round 12
// baseline (307.806 us; speedup 1.0000x reference)
//
#include <hip/hip_runtime.h>
#include <hip/hip_bf16.h>

#define N_ROWS 16384
#define DIN_K  256
#define DOUT_K 64
#define M_COLS 16384
#define LOG2E  1.4426950408889634f

typedef __attribute__((ext_vector_type(8))) short short8;
typedef __attribute__((ext_vector_type(4))) float f32x4;

#define MFMA16 __builtin_amdgcn_mfma_f32_16x16x32_bf16
#define EXP2F  __builtin_amdgcn_exp2f
#define LOG2F  __builtin_amdgcn_logf

__device__ inline unsigned short f32_bf16_rne(float x) {
    unsigned u = __builtin_bit_cast(unsigned, x);
    u += 0x7fffu + ((u >> 16) & 1u);
    return (unsigned short)(u >> 16);
}
__device__ inline float bf16_f32(unsigned short h) {
    unsigned u = ((unsigned)h) << 16;
    return __builtin_bit_cast(float, u);
}

// ---------------------------------------------------------------------------
// Kernel 1: before = (X @ W) * log2(e); split to bf16 hi/lo; per-row exp bound
// ---------------------------------------------------------------------------
__global__ __launch_bounds__(256) void k_before(
    const float* __restrict__ X, const float* __restrict__ W,
    float* __restrict__ off2,
    unsigned short* __restrict__ bh, unsigned short* __restrict__ bl)
{
    const int row  = blockIdx.x * 4 + (threadIdx.x >> 6);
    const int lane = threadIdx.x & 63;
    const float* xr = X + (size_t)row * DIN_K;
    float acc = 0.f;
    #pragma unroll 8
    for (int d = 0; d < DIN_K; ++d)
        acc = fmaf(xr[d], W[d * DOUT_K + lane], acc);
    const float bs = acc * LOG2E;
    const unsigned short hs = f32_bf16_rne(bs);
    const float hf = bf16_f32(hs);
    const unsigned short ls = f32_bf16_rne(bs - hf);
    bh[row * DOUT_K + lane] = hs;
    bl[row * DOUT_K + lane] = ls;
    float t = fmaxf(bs, 0.f);
    #pragma unroll
    for (int m = 1; m < 64; m <<= 1) t += __shfl_xor(t, m, 64);
    if (lane == 0) off2[row] = t;
}

// ---------------------------------------------------------------------------
// Kernel 2: pack adjacency into MFMA A-fragment order, bf16 hi/lo (unchanged).
// chunk c, ks: lane l holds adj[k = ks*32 + (l>>4)*8 + i][c*16 + (l&15)]
// ---------------------------------------------------------------------------
__global__ __launch_bounds__(256) void k_pack(
    const float* __restrict__ A,
    unsigned short* __restrict__ ahp, unsigned short* __restrict__ alp)
{
    const int wid   = blockIdx.x * 4 + (threadIdx.x >> 6);  // 0..2047
    const int lane  = threadIdx.x & 63;
    const int chunk = wid >> 1, ks = wid & 1;
    const int col   = chunk * 16 + (lane & 15);
    const int kb    = ks * 32 + ((lane >> 4) * 8);
    const size_t base = ((size_t)(chunk * 2 + ks) * 64 + lane) * 8;
    #pragma unroll
    for (int i = 0; i < 8; ++i) {
        const float a = A[(size_t)(kb + i) * M_COLS + col];
        const unsigned short hs = f32_bf16_rne(a);
        ahp[base + i] = hs;
        alp[base + i] = f32_bf16_rne(a - bf16_f32(hs));
    }
}

// ---------------------------------------------------------------------------
// Kernel 3: fused scores + softmax.
//   Pass 1 (unchanged): 2-term denominators, per-wave rotated streaming.
//   Pass 2: 64 slabs of 64 rows x 256 cols, DOUBLE-BUFFERED LDS transpose
//   (sout0/sout1, 133 KB total, 1 block/CU) -> one barrier per slab; the
//   vmcnt(0) store drain at each barrier overlaps the next slab's MFMA/exp2.
//   Stores are 64-lane x 16B = 1KB full-DRAM-page nontemporal bursts.
// ---------------------------------------------------------------------------
__global__ __launch_bounds__(512, 2) void k_main(
    const unsigned short* __restrict__ bh, const unsigned short* __restrict__ bl,
    const unsigned short* __restrict__ ahp, const unsigned short* __restrict__ alp,
    const float* __restrict__ off2, float* __restrict__ out)
{
    __shared__ float lds[8][64];
    __shared__ float sout0[64 * 260];   // slab buffer A (+4 col pad: 2-way banks)
    __shared__ float sout1[64 * 260];   // slab buffer B
    const int wave = threadIdx.x >> 6;
    const int lane = threadIdx.x & 63;
    const int lrow = lane & 15;   // out-row within tile (D col)
    const int lgrp = lane >> 4;   // out-col quad (D row group)
    const int r0   = blockIdx.x * 64;
    const int rot  = (((blockIdx.x << 3) | wave) * 53) & 127;
    const int cbase = wave * 128;

#define CIDX(j) (cbase + (((j) + rot) & 127))

    // Stationary before^T fragments (B operand), 4 row-tiles, hi/lo.
    short8 bHf[4][2], bLf[4][2];
    #pragma unroll
    for (int rt = 0; rt < 4; ++rt)
        #pragma unroll
        for (int ks = 0; ks < 2; ++ks) {
            const size_t o = (size_t)(r0 + rt * 16 + lrow) * DOUT_K + ks * 32 + lgrp * 8;
            bHf[rt][ks] = *reinterpret_cast<const short8*>(bh + o);
            bLf[rt][ks] = *reinterpret_cast<const short8*>(bl + o);
        }

    float negoff[4];
    #pragma unroll
    for (int rt = 0; rt < 4; ++rt)
        negoff[rt] = -off2[r0 + rt * 16 + lrow];

    float lsum[4] = {0.f, 0.f, 0.f, 0.f};

#define LOADA(H0, H1, c) {                                                  \
    const size_t _b = (size_t)((c) * 2) * 512 + lane * 8;                   \
    H0 = *reinterpret_cast<const short8*>(ahp + _b);                        \
    H1 = *reinterpret_cast<const short8*>(ahp + _b + 512); }

#define LOADB(H0, H1, L0, L1, c) {                                          \
    const size_t _b = (size_t)((c) * 2) * 512 + lane * 8;                   \
    H0 = *reinterpret_cast<const short8*>(ahp + _b);                        \
    H1 = *reinterpret_cast<const short8*>(ahp + _b + 512);                  \
    L0 = *reinterpret_cast<const short8*>(alp + _b);                        \
    L1 = *reinterpret_cast<const short8*>(alp + _b + 512); }

#define BODY1(H0, H1)                                                       \
    _Pragma("unroll")                                                       \
    for (int rt = 0; rt < 4; ++rt) {                                        \
        f32x4 acc = { negoff[rt], negoff[rt], negoff[rt], negoff[rt] };     \
        acc = MFMA16(H0, bHf[rt][0], acc, 0, 0, 0);                         \
        acc = MFMA16(H1, bHf[rt][1], acc, 0, 0, 0);                         \
        acc = MFMA16(H0, bLf[rt][0], acc, 0, 0, 0);                         \
        acc = MFMA16(H1, bLf[rt][1], acc, 0, 0, 0);                         \
        lsum[rt] += (EXP2F(acc[0]) + EXP2F(acc[1]))                         \
                  + (EXP2F(acc[2]) + EXP2F(acc[3])); }

    short8 cH0, cH1, nH0, nH1;

    // ---- pass 1: denominators (2-term, ahp-only, rotated ping-pong) ----
    LOADA(cH0, cH1, CIDX(0));
    for (int j = 0; j < 128; j += 2) {
        LOADA(nH0, nH1, CIDX(j + 1));
        BODY1(cH0, cH1);
        LOADA(cH0, cH1, CIDX(j + 2));
        BODY1(nH0, nH1);
    }

    #pragma unroll
    for (int rt = 0; rt < 4; ++rt) {
        float v = lsum[rt];
        v += __shfl_xor(v, 16, 64);
        v += __shfl_xor(v, 32, 64);
        lsum[rt] = v;
    }
    if (lgrp == 0) {
        #pragma unroll
        for (int rt = 0; rt < 4; ++rt)
            lds[wave][rt * 16 + lrow] = lsum[rt];
    }
    __syncthreads();

    float base2[4];
    #pragma unroll
    for (int rt = 0; rt < 4; ++rt) {
        const int rl = rt * 16 + lrow;
        float tot = ((lds[0][rl] + lds[1][rl]) + (lds[2][rl] + lds[3][rl]))
                  + ((lds[4][rl] + lds[5][rl]) + (lds[6][rl] + lds[7][rl]));
        base2[rt] = negoff[rt] - LOG2F(tot);
    }

    // ---- pass 2: double-buffered slab-transposed full-page stores ----
    const int rotb = (blockIdx.x * 37) & 63;
    const int k0 = wave * 2, k1 = wave * 2 + 1;

#define LOADPAIR(H00,H01,L00,L01, H10,H11,L10,L11, sp) {                    \
    const int _cc = (sp) * 16 + k0;                                         \
    LOADB(H00, H01, L00, L01, _cc);                                         \
    LOADB(H10, H11, L10, L11, _cc + 1); }

#define BODY2L(H0, H1, L0, L1, kk, BUF)                                     \
    _Pragma("unroll")                                                       \
    for (int rt = 0; rt < 4; ++rt) {                                        \
        f32x4 acc = { base2[rt], base2[rt], base2[rt], base2[rt] };         \
        acc = MFMA16(H0, bHf[rt][0], acc, 0, 0, 0);                         \
        acc = MFMA16(H1, bHf[rt][1], acc, 0, 0, 0);                         \
        acc = MFMA16(L0, bHf[rt][0], acc, 0, 0, 0);                         \
        acc = MFMA16(L1, bHf[rt][1], acc, 0, 0, 0);                         \
        acc = MFMA16(H0, bLf[rt][0], acc, 0, 0, 0);                         \
        acc = MFMA16(H1, bLf[rt][1], acc, 0, 0, 0);                         \
        f32x4 o4 = { EXP2F(acc[0]), EXP2F(acc[1]),                          \
                     EXP2F(acc[2]), EXP2F(acc[3]) };                        \
        *reinterpret_cast<f32x4*>(                                          \
            &BUF[(rt * 16 + lrow) * 260 + (kk) * 16 + lgrp * 4]) = o4; }

#define STOREPHASE(sp, BUF) {                                               \
    const size_t _cb = (size_t)(sp) * 256;                                  \
    _Pragma("unroll")                                                       \
    for (int i = 0; i < 8; ++i) {                                           \
        const int _rw = wave * 8 + i;                                       \
        const f32x4 v = *reinterpret_cast<const f32x4*>(                    \
            &BUF[_rw * 260 + lane * 4]);                                    \
        __builtin_nontemporal_store(v, reinterpret_cast<f32x4*>(            \
            out + (size_t)(r0 + _rw) * M_COLS + _cb + lane * 4)); } }

    short8 A0H0,A0H1,A0L0,A0L1, A1H0,A1H1,A1L0,A1L1;
    short8 B0H0,B0H1,B0L0,B0L1, B1H0,B1H1,B1L0,B1L1;

    // prologue: compute slab sp(0) into sout0, prefetch sp(1) into B regs
    LOADPAIR(A0H0,A0H1,A0L0,A0L1, A1H0,A1H1,A1L0,A1L1, rotb);
    BODY2L(A0H0,A0H1,A0L0,A0L1, k0, sout0);
    BODY2L(A1H0,A1H1,A1L0,A1L1, k1, sout0);
    LOADPAIR(B0H0,B0H1,B0L0,B0L1, B1H0,B1H1,B1L0,B1L1, (1 + rotb) & 63);
    __syncthreads();

    for (int s = 0; s < 62; s += 2) {
        const int spE = (s + rotb) & 63;
        const int spO = (s + 1 + rotb) & 63;
        // store slab s (sout0), compute slab s+1 (B regs) into sout1
        STOREPHASE(spE, sout0);
        LOADPAIR(A0H0,A0H1,A0L0,A0L1, A1H0,A1H1,A1L0,A1L1, (s + 2 + rotb) & 63);
        BODY2L(B0H0,B0H1,B0L0,B0L1, k0, sout1);
        BODY2L(B1H0,B1H1,B1L0,B1L1, k1, sout1);
        __syncthreads();
        // store slab s+1 (sout1), compute slab s+2 (A regs) into sout0
        STOREPHASE(spO, sout1);
        LOADPAIR(B0H0,B0H1,B0L0,B0L1, B1H0,B1H1,B1L0,B1L1, (s + 3 + rotb) & 63);
        BODY2L(A0H0,A0H1,A0L0,A0L1, k0, sout0);
        BODY2L(A1H0,A1H1,A1L0,A1L1, k1, sout0);
        __syncthreads();
    }
    // epilogue: slabs 62, 63
    STOREPHASE((62 + rotb) & 63, sout0);
    BODY2L(B0H0,B0H1,B0L0,B0L1, k0, sout1);
    BODY2L(B1H0,B1H1,B1L0,B1L1, k1, sout1);
    __syncthreads();
    STOREPHASE((63 + rotb) & 63, sout1);
#undef CIDX
#undef LOADA
#undef LOADB
#undef BODY1
#undef LOADPAIR
#undef BODY2L
#undef STOREPHASE
}

extern "C" void kernel_launch(void* const* d_in, const int* in_sizes, int n_in,
                              void* d_out, int out_size, void* d_ws, size_t ws_size,
                              hipStream_t stream) {
    const float* X = (const float*)d_in[0];   // [16384, 256]
    const float* A = (const float*)d_in[1];   // [64, 16384]
    const float* W = (const float*)d_in[2];   // [256, 64]
    float* out = (float*)d_out;               // [16384, 16384]

    char* wsb = (char*)d_ws;
    float*          off2 = (float*)wsb;                                   // 64 KB
    unsigned short* bh   = (unsigned short*)(wsb + (1u << 16));           // 2 MB
    unsigned short* bl   = (unsigned short*)(wsb + (1u << 16) + (1u << 21));
    unsigned short* ahp  = (unsigned short*)(wsb + (1u << 16) + 2u * (1u << 21));
    unsigned short* alp  = (unsigned short*)(wsb + (1u << 16) + 3u * (1u << 21));

    hipLaunchKernelGGL(k_before, dim3(N_ROWS / 4), dim3(256), 0, stream, X, W, off2, bh, bl);
    hipLaunchKernelGGL(k_pack,   dim3(512),        dim3(256), 0, stream, A, ahp, alp);
    hipLaunchKernelGGL(k_main,   dim3(256),        dim3(512), 0, stream, bh, bl, ahp, alp, off2, out);
}